// Round 13
// baseline (313.538 us; speedup 1.0000x reference)
//
#include <hip/hip_runtime.h>
#include <hip/hip_bf16.h>
#include <math.h>

using bf16 = __hip_bfloat16;
typedef __attribute__((ext_vector_type(8))) short short8;
typedef __attribute__((ext_vector_type(4))) float floatx4;

// ---------------------------------------------------------------- helpers
__device__ inline void gl_lds16(const void* g, void* l) {
  __builtin_amdgcn_global_load_lds(
      (const __attribute__((address_space(1))) unsigned int*)g,
      (__attribute__((address_space(3))) unsigned int*)l,
      16, 0, 0);
}
__device__ inline float eluf(float x) { return x > 0.f ? x : __expf(x) - 1.f; }
__device__ inline float bf2f(unsigned short h) {
  return __uint_as_float(((unsigned)h) << 16);
}
__device__ inline void bf16x8_fma(short8 r, float w, float* acc) {
#pragma unroll
  for (int k = 0; k < 8; k++) acc[k] += w * bf2f((unsigned short)r[k]);
}

// ---------------------------------------------------------------- probe + zero counters
__global__ void probe_zero(const unsigned short* __restrict__ x, int* __restrict__ flag,
                           int* __restrict__ zbase, int zwords) {
  if (blockIdx.x == 0) {
    __shared__ int s;
    int t = threadIdx.x;
    if (t == 0) s = 0;
    __syncthreads();
    int bad = 0;
    for (int i = t; i < 1024; i += 256) {
      unsigned short h = x[2 * i];
      unsigned e = (h >> 7) & 0xFF;
      if (e >= 0xE5) bad = 1;
    }
    if (bad) atomicOr(&s, 1);
    __syncthreads();
    if (t == 0) flag[0] = s;
  } else {
    int i = (blockIdx.x - 1) * 1024 + threadIdx.x * 4;
    if (i < zwords) {
      zbase[i] = 0; zbase[i + 1] = 0; zbase[i + 2] = 0; zbase[i + 3] = 0;
    }
  }
}

// ---------------------------------------------------------------- fused prep
__global__ void prep_all(
    const void* X, bf16* __restrict__ Xb, int nx,
    const void* W11, const void* W12, const void* W21, const void* W22,
    const void* W31, const void* W32,
    bf16* Wt11, bf16* Wt12, bf16* Wt2cat, bf16* Wt3cat,
    const void* b11, const void* b12, const void* b21, const void* b22,
    const void* b31, const void* b32, const void* aw1, const void* aw2, const void* aw3,
    float* ob11, float* ob12, float* ob21, float* ob22, float* ob31, float* ob32,
    float* ow1, float* ow2, float* ow3,
    const int* __restrict__ dst1, int E1, const int* __restrict__ dst2, int E2,
    int* __restrict__ deg1, int* __restrict__ deg2,
    const int* __restrict__ flag) {
  const bool f32 = *flag != 0;
  int b = blockIdx.x;
  const int xbBlocks = nx / 2048;
  if (b < 2176) {
    __shared__ bf16 tile[32][33];
    const void* in; bf16* out; int K, N, tt;
    if (b < 512)       { in = W11; out = Wt11; K = 512;  N = 1024; tt = b; }
    else if (b < 1024) { in = W12; out = Wt12; K = 512;  N = 1024; tt = b - 512; }
    else if (b < 1536) { in = W21; out = Wt2cat; K = 1024; N = 512; tt = b - 1024; }
    else if (b < 2048) { in = W22; out = Wt2cat + (size_t)512 * 1024; K = 1024; N = 512; tt = b - 1536; }
    else if (b < 2112) { in = W31; out = Wt3cat; K = 512; N = 128; tt = b - 2048; }
    else               { in = W32; out = Wt3cat + (size_t)128 * 512; K = 512; N = 128; tt = b - 2112; }
    int tilesx = N / 32;
    int bx = (tt % tilesx) * 32;
    int by = (tt / tilesx) * 32;
    int tx = threadIdx.x & 31, ty = threadIdx.x >> 5;
#pragma unroll
    for (int i = 0; i < 32; i += 8) {
      size_t idx = (size_t)(by + ty + i) * N + (bx + tx);
      tile[ty + i][tx] = f32 ? __float2bfloat16(((const float*)in)[idx])
                             : ((const bf16*)in)[idx];
    }
    __syncthreads();
#pragma unroll
    for (int i = 0; i < 32; i += 8)
      out[(size_t)(bx + ty + i) * K + (by + tx)] = tile[tx][ty + i];
    return;
  }
  b -= 2176;
  if (b < xbBlocks) {
    int e = (b * 256 + threadIdx.x) * 8;
    if (f32) {
      const float* src = (const float*)X + e;
      short8 r;
#pragma unroll
      for (int k = 0; k < 8; k++)
        r[k] = (short)__bfloat16_as_ushort(__float2bfloat16(src[k]));
      *(short8*)(Xb + e) = r;
    } else {
      *(short8*)(Xb + e) = *(const short8*)((const bf16*)X + e);
    }
    return;
  }
  b -= xbBlocks;
  if (b < 20) {
    auto cv = [&](const void* p, int i) -> float {
      return f32 ? ((const float*)p)[i] : __bfloat162float(((const bf16*)p)[i]);
    };
    int t = b * 256 + threadIdx.x;
    if (t < 1024) ob11[t] = cv(b11, t);
    else if (t < 2048) ob12[t - 1024] = cv(b12, t - 1024);
    else if (t < 2560) ob21[t - 2048] = cv(b21, t - 2048);
    else if (t < 3072) ob22[t - 2560] = cv(b22, t - 2560);
    else if (t < 3200) ob31[t - 3072] = cv(b31, t - 3072);
    else if (t < 3328) ob32[t - 3200] = cv(b32, t - 3200);
    else if (t < 4992) {
      int j = t - 3328;
      const void* src; float* dst; int jj;
      if (j < 1024)      { src = aw1; dst = ow1; jj = j; }
      else if (j < 1536) { src = aw2; dst = ow2; jj = j - 1024; }
      else               { src = aw3; dst = ow3; jj = j - 1536; }
      float e0 = cv(src, 2 * jj), e1 = cv(src, 2 * jj + 1);
      float mx = fmaxf(e0, e1);
      float w0 = expf(e0 - mx), w1 = expf(e1 - mx);
      float inv = 1.f / (w0 + w1);
      dst[2 * jj] = w0 * inv;
      dst[2 * jj + 1] = w1 * inv;
    }
    return;
  }
  b -= 20;
  {
    int e = b * 256 + threadIdx.x;
    if (e < E1) atomicAdd(&deg1[dst1[e]], 1);
    else if (e < E1 + E2) atomicAdd(&deg2[dst2[e - E1]], 1);
  }
}

// ---------------------------------------------------------------- scan (wave-shuffle)
__global__ void scan2_kernel(const int* __restrict__ deg1, int* __restrict__ off1,
                             float* __restrict__ dinv1,
                             const int* __restrict__ deg2, int* __restrict__ off2,
                             float* __restrict__ dinv2, int n) {
  const int* deg = blockIdx.x ? deg2 : deg1;
  int* off = blockIdx.x ? off2 : off1;
  float* dinv = blockIdx.x ? dinv2 : dinv1;
  __shared__ int wsum[16];
  __shared__ int carry_s;
  const int t = threadIdx.x;
  const int waveid = t >> 6;
  const int lane = t & 63;
  if (t == 0) carry_s = 0;
  __syncthreads();
  for (int base = 0; base < n; base += 1024) {
    int i = base + t;
    int orig = (i < n) ? deg[i] : 0;
    int v = orig;
#pragma unroll
    for (int d = 1; d < 64; d <<= 1) {
      int u = __shfl_up(v, d, 64);
      if (lane >= d) v += u;
    }
    if (lane == 63) wsum[waveid] = v;
    __syncthreads();
    if (waveid == 0 && lane < 16) {
      int s = wsum[lane];
#pragma unroll
      for (int d = 1; d < 16; d <<= 1) {
        int u = __shfl_up(s, d, 64);
        if (lane >= d) s += u;
      }
      wsum[lane] = s;
    }
    __syncthreads();
    int woff = waveid ? wsum[waveid - 1] : 0;
    int incl = v + woff;
    int carry = carry_s;
    if (i < n) {
      off[i]  = carry + incl - orig;
      dinv[i] = rsqrtf((float)(orig + 1));
    }
    __syncthreads();
    if (t == 1023) carry_s = carry + wsum[15];
    __syncthreads();
  }
  if (t == 0) off[n] = carry_s;
}

__global__ void csr_fused(const int* __restrict__ src1, const int* __restrict__ dst1, int E1,
                          const int* __restrict__ src2, const int* __restrict__ dst2, int E2,
                          const int* __restrict__ off1, int* __restrict__ cur1,
                          const float* __restrict__ dinv1,
                          int* __restrict__ cs1, float* __restrict__ cw1,
                          const int* __restrict__ off2, int* __restrict__ cur2,
                          const float* __restrict__ dinv2,
                          int* __restrict__ cs2, float* __restrict__ cw2) {
  int e = blockIdx.x * 256 + threadIdx.x;
  if (e < E1) {
    int d = dst1[e], s = src1[e];
    int slot = off1[d] + atomicAdd(&cur1[d], 1);
    cs1[slot] = s;
    cw1[slot] = dinv1[s];
  } else if (e < E1 + E2) {
    int ee = e - E1;
    int d = dst2[ee], s = src2[ee];
    int slot = off2[d] + atomicAdd(&cur2[d], 1);
    cs2[slot] = s;
    cw2[slot] = dinv2[s];
  }
}

// ---------------------------------------------------------------- gather loop (8/4/2/1 unroll)
template <int LD>
__device__ inline void gather_accum(const bf16* __restrict__ base,
                                    const int* __restrict__ cs, const float* __restrict__ cw,
                                    int s, int e, float* acc) {
  int i = s;
  for (; i + 8 <= e; i += 8) {
    short8 r[8]; float w[8];
#pragma unroll
    for (int k = 0; k < 8; k++) {
      r[k] = *(const short8*)(base + (size_t)cs[i + k] * LD);
      w[k] = cw[i + k];
    }
#pragma unroll
    for (int k = 0; k < 8; k++) bf16x8_fma(r[k], w[k], acc);
  }
  for (; i + 4 <= e; i += 4) {
    short8 r[4]; float w[4];
#pragma unroll
    for (int k = 0; k < 4; k++) {
      r[k] = *(const short8*)(base + (size_t)cs[i + k] * LD);
      w[k] = cw[i + k];
    }
#pragma unroll
    for (int k = 0; k < 4; k++) bf16x8_fma(r[k], w[k], acc);
  }
  for (; i + 2 <= e; i += 2) {
    short8 r0 = *(const short8*)(base + (size_t)cs[i] * LD);
    short8 r1 = *(const short8*)(base + (size_t)cs[i + 1] * LD);
    bf16x8_fma(r0, cw[i], acc);
    bf16x8_fma(r1, cw[i + 1], acc);
  }
  if (i < e) {
    short8 r0 = *(const short8*)(base + (size_t)cs[i] * LD);
    bf16x8_fma(r0, cw[i], acc);
  }
}

// ---------------------------------------------------------------- input-side agg (layer 1)
__global__ __launch_bounds__(256) void aggx_kernel(
    const bf16* __restrict__ X,
    const int* __restrict__ off1, const int* __restrict__ cs1, const float* __restrict__ cw1,
    const int* __restrict__ off2, const int* __restrict__ cs2, const float* __restrict__ cw2,
    const float* __restrict__ dinv1, const float* __restrict__ dinv2,
    bf16* __restrict__ outA, bf16* __restrict__ outB, int n) {
  const int lin = blockIdx.x;
  const int slice = lin & 7;
  const int vg = lin >> 3;
  const int t = threadIdx.x;
  const int v = vg * 32 + t / 8;
  if (v >= n) return;
  const int c = slice * 64 + (t & 7) * 8;
  const bf16* __restrict__ base = X + c;

  float a[8], b[8];
#pragma unroll
  for (int k = 0; k < 8; k++) { a[k] = 0.f; b[k] = 0.f; }

  gather_accum<512>(base, cs1, cw1, off1[v], off1[v + 1], a);
  gather_accum<512>(base, cs2, cw2, off2[v], off2[v + 1], b);

  short8 self = *(const short8*)(base + (size_t)v * 512);
  const float dv1 = dinv1[v], dv2 = dinv2[v];
  short8 ra, rb;
#pragma unroll
  for (int k = 0; k < 8; k++) {
    float xs = bf2f((unsigned short)self[k]);
    ra[k] = (short)__bfloat16_as_ushort(__float2bfloat16(dv1 * a[k] + dv1 * dv1 * xs));
    rb[k] = (short)__bfloat16_as_ushort(__float2bfloat16(dv2 * b[k] + dv2 * dv2 * xs));
  }
  *(short8*)(outA + (size_t)v * 512 + c) = ra;
  *(short8*)(outB + (size_t)v * 512 + c) = rb;
}

// ---------------------------------------------------------------- GEMM (m97-style, XOR-swizzled LDS)
__device__ inline void gemm_body(const bf16* __restrict__ A, const bf16* __restrict__ Bt,
                                 bf16* __restrict__ C, int M, int K, int N,
                                 int m0, int n0) {
  __shared__ bf16 As[128 * 32];
  __shared__ bf16 Bs[128 * 32];
  const int tid = threadIdx.x;
  const int wave = tid >> 6;
  const int lane = tid & 63;
  const int quad = lane >> 4;
  const int l16 = lane & 15;
  const int wr = (wave >> 1) * 64;
  const int wc = (wave & 1) * 64;
  const int r_sub = lane >> 2;
  const int cb = (((lane & 3) ^ ((lane >> 3) & 3)) * 16);
  const int rsw = (l16 >> 1) & 3;

  floatx4 acc[4][4];
#pragma unroll
  for (int i = 0; i < 4; i++)
#pragma unroll
    for (int j = 0; j < 4; j++) acc[i][j] = (floatx4){0.f, 0.f, 0.f, 0.f};

  for (int k0 = 0; k0 < K; k0 += 32) {
    __syncthreads();
#pragma unroll
    for (int j = 0; j < 2; ++j) {
      int p = wave * 2 + j;
      int ra = p * 16 + r_sub;
      int grow = m0 + ra; if (grow >= M) grow = M - 1;
      gl_lds16((const char*)(A + (size_t)grow * K + k0) + cb, (char*)As + p * 1024);
      int rb = n0 + p * 16 + r_sub;
      gl_lds16((const char*)(Bt + (size_t)rb * K + k0) + cb, (char*)Bs + p * 1024);
    }
    __syncthreads();

    short8 af[4], bfr[4];
#pragma unroll
    for (int i = 0; i < 4; i++)
      af[i] = *(const short8*)(As + (wr + i * 16 + l16) * 32 + (quad ^ rsw) * 8);
#pragma unroll
    for (int j = 0; j < 4; j++)
      bfr[j] = *(const short8*)(Bs + (wc + j * 16 + l16) * 32 + (quad ^ rsw) * 8);
#pragma unroll
    for (int i = 0; i < 4; i++)
#pragma unroll
      for (int j = 0; j < 4; j++)
        acc[i][j] = __builtin_amdgcn_mfma_f32_16x16x32_bf16(af[i], bfr[j], acc[i][j], 0, 0, 0);
  }

#pragma unroll
  for (int i = 0; i < 4; i++) {
#pragma unroll
    for (int r = 0; r < 4; r++) {
      int row = m0 + wr + i * 16 + quad * 4 + r;
      if (row < M) {
#pragma unroll
        for (int j = 0; j < 4; j++) {
          int col = n0 + wc + j * 16 + l16;
          C[(size_t)row * N + col] = __float2bfloat16(acc[i][j][r]);
        }
      }
    }
  }
}

__global__ __launch_bounds__(256) void gemm128_sw(
    const bf16* __restrict__ A0, const bf16* __restrict__ Bt0, bf16* __restrict__ C0,
    const bf16* __restrict__ A1, const bf16* __restrict__ Bt1, bf16* __restrict__ C1,
    int M, int K, int N, int mtilesPerHalf, int mtTotal, int ntLog2) {
  int lin = blockIdx.x;
  int g = lin & 7;
  int s = lin >> 3;
  int n_t = s & ((1 << ntLog2) - 1);
  int m_t = g + 8 * (s >> ntLog2);
  if (m_t >= mtTotal) return;
  int half = (m_t >= mtilesPerHalf) ? 1 : 0;
  int m_local = m_t - half * mtilesPerHalf;
  const bf16* A = half ? A1 : A0;
  const bf16* Bt = half ? Bt1 : Bt0;
  bf16* C = half ? C1 : C0;
  gemm_body(A, Bt, C, M, K, N, m_local * 128, n_t * 128);
}

// ---------------------------------------------------------------- layer-1 fused GEMM
// 512 threads, 128x128 tile, both GEMMs: staging ratio = plain gemm128 (128 elems/MFMA),
// acc = 2 GEMMs x 4x2 x4 = 64 VGPR/lane. launch_bounds(512,4) targets VGPR<=128 -> 2 blk/CU.
__global__ __launch_bounds__(512, 4) void gemm_l1f(
    const bf16* __restrict__ Aa, const bf16* __restrict__ Bta,
    const bf16* __restrict__ Ab, const bf16* __restrict__ Btb,
    const float* __restrict__ ba, const float* __restrict__ bb,
    const float* __restrict__ w01, bf16* __restrict__ out,
    int M, int K, int N, int mtiles) {
  int lin = blockIdx.x;
  int g = lin & 7;
  int s = lin >> 3;
  int n_t = s & 7;                 // 8 n-tiles of 128
  int m_t = g + 8 * (s >> 3);
  if (m_t >= mtiles) return;
  const int m0 = m_t * 128, n0 = n_t * 128;

  __shared__ bf16 Asa[128 * 32];
  __shared__ bf16 Asb[128 * 32];
  __shared__ bf16 Bsa[128 * 32];
  __shared__ bf16 Bsb[128 * 32];
  const int tid = threadIdx.x;
  const int wave = tid >> 6;        // 0..7
  const int lane = tid & 63;
  const int quad = lane >> 4;
  const int l16 = lane & 15;
  const int wr = (wave >> 2) * 64;  // 0,64
  const int wc = (wave & 3) * 32;   // 0,32,64,96
  const int r_sub = lane >> 2;
  const int cb = (((lane & 3) ^ ((lane >> 3) & 3)) * 16);
  const int rsw = (l16 >> 1) & 3;

  // staging: wave w owns buffer (w>>1); portions (w&1)*4 + j (j=0..3)
  const int buf = wave >> 1;        // 0:Asa 1:Asb 2:Bsa 3:Bsb
  const bf16* gsrc = (buf == 0) ? Aa : (buf == 1) ? Ab : (buf == 2) ? Bta : Btb;
  bf16* lds = (buf == 0) ? Asa : (buf == 1) ? Asb : (buf == 2) ? Bsa : Bsb;
  const int base_row = (buf < 2) ? m0 : n0;
  const bool isA = (buf < 2);

  floatx4 acca[4][2], accb[4][2];
#pragma unroll
  for (int i = 0; i < 4; i++)
#pragma unroll
    for (int j = 0; j < 2; j++) {
      acca[i][j] = (floatx4){0.f, 0.f, 0.f, 0.f};
      accb[i][j] = (floatx4){0.f, 0.f, 0.f, 0.f};
    }

  for (int k0 = 0; k0 < K; k0 += 32) {
    __syncthreads();
#pragma unroll
    for (int j = 0; j < 4; ++j) {
      int pr = (wave & 1) * 4 + j;             // 0..7 within buffer
      int row = pr * 16 + r_sub;
      int grow = base_row + row;
      if (isA && grow >= M) grow = M - 1;       // N multiple of 128: B unguarded
      gl_lds16((const char*)(gsrc + (size_t)grow * K + k0) + cb, (char*)lds + pr * 1024);
    }
    __syncthreads();

    short8 afa[4], afb[4], bfa[2], bfb[2];
#pragma unroll
    for (int i = 0; i < 4; i++) {
      afa[i] = *(const short8*)(Asa + (wr + i * 16 + l16) * 32 + (quad ^ rsw) * 8);
      afb[i] = *(const short8*)(Asb + (wr + i * 16 + l16) * 32 + (quad ^ rsw) * 8);
    }
#pragma unroll
    for (int j = 0; j < 2; j++) {
      bfa[j] = *(const short8*)(Bsa + (wc + j * 16 + l16) * 32 + (quad ^ rsw) * 8);
      bfb[j] = *(const short8*)(Bsb + (wc + j * 16 + l16) * 32 + (quad ^ rsw) * 8);
    }
#pragma unroll
    for (int i = 0; i < 4; i++)
#pragma unroll
      for (int j = 0; j < 2; j++) {
        acca[i][j] = __builtin_amdgcn_mfma_f32_16x16x32_bf16(afa[i], bfa[j], acca[i][j], 0, 0, 0);
        accb[i][j] = __builtin_amdgcn_mfma_f32_16x16x32_bf16(afb[i], bfb[j], accb[i][j], 0, 0, 0);
      }
  }

#pragma unroll
  for (int j = 0; j < 2; j++) {
    int col = n0 + wc + j * 16 + l16;
    float baj = ba[col], bbj = bb[col];
    float w0 = w01[2 * col], w1 = w01[2 * col + 1];
#pragma unroll
    for (int i = 0; i < 4; i++) {
#pragma unroll
      for (int r = 0; r < 4; r++) {
        int row = m0 + wr + i * 16 + quad * 4 + r;
        if (row < M) {
          float x = eluf(acca[i][j][r] + baj);
          float y = eluf(accb[i][j][r] + bbj);
          out[(size_t)row * N + col] = __float2bfloat16(x * w0 + y * w1);
        }
      }
    }
  }
}

// ---------------------------------------------------------------- layer-2 agg, XCD channel-sliced
__global__ __launch_bounds__(256) void agg2_kernel(
    const bf16* __restrict__ Ha, const bf16* __restrict__ Hb,  // ldH = 1024
    const int* __restrict__ off1, const int* __restrict__ cs1, const float* __restrict__ cw1,
    const int* __restrict__ off2, const int* __restrict__ cs2, const float* __restrict__ cw2,
    const float* __restrict__ dinv1, const float* __restrict__ dinv2,
    const float* __restrict__ ba, const float* __restrict__ bb,
    const float* __restrict__ w01, bf16* __restrict__ out, int n) {
  const int lin = blockIdx.x;
  const int slice = lin & 7;
  const int vg = lin >> 3;
  const int t = threadIdx.x;
  const int v = vg * 32 + t / 8;
  if (v >= n) return;
  const int c = slice * 64 + (t & 7) * 8;
  const bf16* __restrict__ baseA = Ha + c;
  const bf16* __restrict__ baseB = Hb + c;

  float a[8], b[8];
#pragma unroll
  for (int k = 0; k < 8; k++) { a[k] = 0.f; b[k] = 0.f; }

  gather_accum<1024>(baseA, cs1, cw1, off1[v], off1[v + 1], a);
  gather_accum<1024>(baseB, cs2, cw2, off2[v], off2[v + 1], b);

  short8 sa = *(const short8*)(baseA + (size_t)v * 1024);
  short8 sb = *(const short8*)(baseB + (size_t)v * 1024);
  const float dv1 = dinv1[v], dv2 = dinv2[v];

  short8 r;
#pragma unroll
  for (int k = 0; k < 8; k++) {
    float x = eluf(dv1 * a[k] + dv1 * dv1 * bf2f((unsigned short)sa[k]) + ba[c + k]);
    float y = eluf(dv2 * b[k] + dv2 * dv2 * bf2f((unsigned short)sb[k]) + bb[c + k]);
    r[k] = (short)__bfloat16_as_ushort(
        __float2bfloat16(x * w01[2 * (c + k)] + y * w01[2 * (c + k) + 1]));
  }
  *(short8*)(out + (size_t)v * 512 + c) = r;
}

// ---------------------------------------------------------------- layer-3 agg
template <int C, int LD, bool WU>
__global__ __launch_bounds__(256) void agg_out_kernel(
    const bf16* __restrict__ Ha, const bf16* __restrict__ Hb,
    const int* __restrict__ off1, const int* __restrict__ cs1, const float* __restrict__ cw1,
    const int* __restrict__ off2, const int* __restrict__ cs2, const float* __restrict__ cw2,
    const float* __restrict__ dinv1, const float* __restrict__ dinv2,
    const float* __restrict__ ba, const float* __restrict__ bb,
    const float* __restrict__ w01, void* __restrict__ out, int n,
    const int* __restrict__ outflag) {
  constexpr int TPV = C / 8;
  constexpr int G = 256 / TPV;
  const int t = threadIdx.x;
  int v = blockIdx.x * G + t / TPV;
  if (v >= n) return;
  if (WU) v = __builtin_amdgcn_readfirstlane(v);
  const int c = (t % TPV) * 8;
  const bf16* __restrict__ baseA = Ha + c;
  const bf16* __restrict__ baseB = Hb + c;

  float a[8], b[8];
#pragma unroll
  for (int k = 0; k < 8; k++) { a[k] = 0.f; b[k] = 0.f; }

  int s1 = off1[v], e1 = off1[v + 1];
  if (WU) { s1 = __builtin_amdgcn_readfirstlane(s1); e1 = __builtin_amdgcn_readfirstlane(e1); }
  gather_accum<LD>(baseA, cs1, cw1, s1, e1, a);
  int s2 = off2[v], e2 = off2[v + 1];
  if (WU) { s2 = __builtin_amdgcn_readfirstlane(s2); e2 = __builtin_amdgcn_readfirstlane(e2); }
  gather_accum<LD>(baseB, cs2, cw2, s2, e2, b);

  short8 sa = *(const short8*)(baseA + (size_t)v * LD);
  short8 sb = *(const short8*)(baseB + (size_t)v * LD);
  const float dv1 = dinv1[v], dv2 = dinv2[v];

  float r[8];
#pragma unroll
  for (int k = 0; k < 8; k++) {
    float x = eluf(dv1 * a[k] + dv1 * dv1 * bf2f((unsigned short)sa[k]) + ba[c + k]);
    float y = eluf(dv2 * b[k] + dv2 * dv2 * bf2f((unsigned short)sb[k]) + bb[c + k]);
    r[k] = x * w01[2 * (c + k)] + y * w01[2 * (c + k) + 1];
  }

  const bool out_f32 = (outflag != nullptr) && (*outflag != 0);
  size_t oi = (size_t)v * C + c;
  if (out_f32) {
    floatx4 lo = {r[0], r[1], r[2], r[3]};
    floatx4 hi = {r[4], r[5], r[6], r[7]};
    *(floatx4*)((float*)out + oi) = lo;
    *(floatx4*)((float*)out + oi + 4) = hi;
  } else {
    short8 rb;
#pragma unroll
    for (int k = 0; k < 8; k++)
      rb[k] = (short)__bfloat16_as_ushort(__float2bfloat16(r[k]));
    *(short8*)((bf16*)out + oi) = rb;
  }
}

// ---------------------------------------------------------------- host pipeline
extern "C" void kernel_launch(void* const* d_in, const int* in_sizes, int n_in,
                              void* d_out, int out_size, void* d_ws, size_t ws_size,
                              hipStream_t stream) {
  const void* X = d_in[0];
  const int* ei1 = (const int*)d_in[1];
  const int* ei2 = (const int*)d_in[2];
  const int n = in_sizes[0] / 512;
  const int E1 = in_sizes[1] / 2;
  const int E2 = in_sizes[2] / 2;
  const int* src1 = ei1;           const int* dst1 = ei1 + E1;
  const int* src2 = ei2;           const int* dst2 = ei2 + E2;

  auto rnd = [](size_t b) { return (b + 255) & ~(size_t)255; };
  char* p = (char*)d_ws;
  auto alloc = [&](size_t bytes) { char* r = p; p += rnd(bytes); return r; };

  int* flag = (int*)alloc(256);
  int* deg1 = (int*)alloc((size_t)n * 4);
  int* deg2 = (int*)alloc((size_t)n * 4);
  int* cur1 = (int*)alloc((size_t)n * 4);
  int* cur2 = (int*)alloc((size_t)n * 4);
  int* off1 = (int*)alloc((size_t)(n + 1) * 4);
  int* off2 = (int*)alloc((size_t)(n + 1) * 4);
  float* dinv1 = (float*)alloc((size_t)n * 4);
  float* dinv2 = (float*)alloc((size_t)n * 4);
  int* cs1 = (int*)alloc((size_t)E1 * 4);
  float* cw1 = (float*)alloc((size_t)E1 * 4);
  int* cs2 = (int*)alloc((size_t)E2 * 4);
  float* cw2 = (float*)alloc((size_t)E2 * 4);
  bf16* Wt11 = (bf16*)alloc((size_t)512 * 1024 * 2);
  bf16* Wt12 = (bf16*)alloc((size_t)512 * 1024 * 2);
  bf16* Wt2cat = (bf16*)alloc((size_t)1024 * 1024 * 2);
  bf16* Wt3cat = (bf16*)alloc((size_t)256 * 512 * 2);
  float* bf_[6]; int bsz[6] = {1024, 1024, 512, 512, 128, 128};
  for (int i = 0; i < 6; i++) bf_[i] = (float*)alloc((size_t)bsz[i] * 4);
  float* w01_[3]; int asz[3] = {2048, 1024, 256};
  for (int i = 0; i < 3; i++) w01_[i] = (float*)alloc((size_t)asz[i] * 4);
  bf16* Xb = (bf16*)alloc((size_t)n * 512 * 2);
  bf16* aggXa = (bf16*)alloc((size_t)n * 512 * 2);
  bf16* aggXb = (bf16*)alloc((size_t)n * 512 * 2);
  bf16* H1a = (bf16*)alloc((size_t)n * 1024 * 2);
  bf16* act1 = (bf16*)alloc((size_t)n * 1024 * 2);
  bf16* H2cat = H1a;
  bf16* act2 = aggXa;  // dead after gemm_l1f
  bf16* H3cat = aggXb; // dead after gemm_l1f

  // ---- prep: probe + zero counters
  int zwords = (int)(rnd((size_t)n * 4) * 4 / 4);
  probe_zero<<<1 + (zwords + 1023) / 1024, 256, 0, stream>>>(
      (const unsigned short*)X, flag, deg1, zwords);

  // ---- fused prep
  int xbBlocks = (n * 512) / 2048;
  int degBlocks = (E1 + E2 + 255) / 256;
  prep_all<<<2176 + xbBlocks + 20 + degBlocks, 256, 0, stream>>>(
      X, Xb, n * 512,
      d_in[3], d_in[5], d_in[7], d_in[9], d_in[11], d_in[13],
      Wt11, Wt12, Wt2cat, Wt3cat,
      d_in[4], d_in[6], d_in[8], d_in[10], d_in[12], d_in[14],
      d_in[15], d_in[16], d_in[17],
      bf_[0], bf_[1], bf_[2], bf_[3], bf_[4], bf_[5],
      w01_[0], w01_[1], w01_[2],
      dst1, E1, dst2, E2, deg1, deg2, flag);

  scan2_kernel<<<2, 1024, 0, stream>>>(deg1, off1, dinv1, deg2, off2, dinv2, n);
  csr_fused<<<(E1 + E2 + 255) / 256, 256, 0, stream>>>(src1, dst1, E1, src2, dst2, E2,
                                                       off1, cur1, dinv1, cs1, cw1,
                                                       off2, cur2, dinv2, cs2, cw2);

  const int mtiles = (n + 127) / 128;
  auto swgrid = [](int mtTotal, int ntiles) {
    return 8 * ntiles * ((mtTotal + 7) / 8);
  };
  const int vg32 = 8 * ((n + 31) / 32);
  // ---- layer 1: XCD-sliced input agg + fused dual-GEMM/bias/ELU/combine (512 thr, 128x128)
  aggx_kernel<<<vg32, 256, 0, stream>>>(Xb, off1, cs1, cw1, off2, cs2, cw2,
                                        dinv1, dinv2, aggXa, aggXb, n);
  gemm_l1f<<<swgrid(mtiles, 8), 512, 0, stream>>>(
      aggXa, Wt11, aggXb, Wt12, bf_[0], bf_[1], w01_[0], act1, n, 512, 1024, mtiles);
  // ---- layer 2: GEMM + XCD-sliced agg
  gemm128_sw<<<swgrid(mtiles, 8), 256, 0, stream>>>(
      act1, Wt2cat, H2cat, act1, Wt2cat, H2cat, n, 1024, 1024, mtiles, mtiles, 3);
  agg2_kernel<<<vg32, 256, 0, stream>>>(H2cat, H2cat + 512,
                                        off1, cs1, cw1, off2, cs2, cw2,
                                        dinv1, dinv2, bf_[2], bf_[3], w01_[1], act2, n);
  // ---- layer 3
  gemm128_sw<<<swgrid(mtiles, 2), 256, 0, stream>>>(
      act2, Wt3cat, H3cat, act2, Wt3cat, H3cat, n, 512, 256, mtiles, mtiles, 1);
  agg_out_kernel<128, 256, false><<<(n + 15) / 16, 256, 0, stream>>>(
      H3cat, H3cat + 128, off1, cs1, cw1, off2, cs2, cw2,
      dinv1, dinv2, bf_[4], bf_[5], w01_[2], d_out, n, flag);
}

// Round 14
// 305.720 us; speedup vs baseline: 1.0256x; 1.0256x over previous
//
#include <hip/hip_runtime.h>
#include <hip/hip_bf16.h>
#include <math.h>

using bf16 = __hip_bfloat16;
typedef __attribute__((ext_vector_type(8))) short short8;
typedef __attribute__((ext_vector_type(4))) float floatx4;

// ---------------------------------------------------------------- helpers
__device__ inline void gl_lds16(const void* g, void* l) {
  __builtin_amdgcn_global_load_lds(
      (const __attribute__((address_space(1))) unsigned int*)g,
      (__attribute__((address_space(3))) unsigned int*)l,
      16, 0, 0);
}
__device__ inline float eluf(float x) { return x > 0.f ? x : __expf(x) - 1.f; }
__device__ inline float bf2f(unsigned short h) {
  return __uint_as_float(((unsigned)h) << 16);
}
__device__ inline void bf16x8_fma(short8 r, float w, float* acc) {
#pragma unroll
  for (int k = 0; k < 8; k++) acc[k] += w * bf2f((unsigned short)r[k]);
}

// ---------------------------------------------------------------- probe + zero counters
__global__ void probe_zero(const unsigned short* __restrict__ x, int* __restrict__ flag,
                           int* __restrict__ zbase, int zwords) {
  if (blockIdx.x == 0) {
    __shared__ int s;
    int t = threadIdx.x;
    if (t == 0) s = 0;
    __syncthreads();
    int bad = 0;
    for (int i = t; i < 1024; i += 256) {
      unsigned short h = x[2 * i];
      unsigned e = (h >> 7) & 0xFF;
      if (e >= 0xE5) bad = 1;
    }
    if (bad) atomicOr(&s, 1);
    __syncthreads();
    if (t == 0) flag[0] = s;
  } else {
    int i = (blockIdx.x - 1) * 1024 + threadIdx.x * 4;
    if (i < zwords) {
      zbase[i] = 0; zbase[i + 1] = 0; zbase[i + 2] = 0; zbase[i + 3] = 0;
    }
  }
}

// ---------------------------------------------------------------- fused prep
__global__ void prep_all(
    const void* X, bf16* __restrict__ Xb, int nx,
    const void* W11, const void* W12, const void* W21, const void* W22,
    const void* W31, const void* W32,
    bf16* Wt11, bf16* Wt12, bf16* Wt2cat, bf16* Wt3cat,
    const void* b11, const void* b12, const void* b21, const void* b22,
    const void* b31, const void* b32, const void* aw1, const void* aw2, const void* aw3,
    float* ob11, float* ob12, float* ob21, float* ob22, float* ob31, float* ob32,
    float* ow1, float* ow2, float* ow3,
    const int* __restrict__ dst1, int E1, const int* __restrict__ dst2, int E2,
    int* __restrict__ deg1, int* __restrict__ deg2,
    const int* __restrict__ flag) {
  const bool f32 = *flag != 0;
  int b = blockIdx.x;
  const int xbBlocks = nx / 2048;
  if (b < 2176) {
    __shared__ bf16 tile[32][33];
    const void* in; bf16* out; int K, N, tt;
    if (b < 512)       { in = W11; out = Wt11; K = 512;  N = 1024; tt = b; }
    else if (b < 1024) { in = W12; out = Wt12; K = 512;  N = 1024; tt = b - 512; }
    else if (b < 1536) { in = W21; out = Wt2cat; K = 1024; N = 512; tt = b - 1024; }
    else if (b < 2048) { in = W22; out = Wt2cat + (size_t)512 * 1024; K = 1024; N = 512; tt = b - 1536; }
    else if (b < 2112) { in = W31; out = Wt3cat; K = 512; N = 128; tt = b - 2048; }
    else               { in = W32; out = Wt3cat + (size_t)128 * 512; K = 512; N = 128; tt = b - 2112; }
    int tilesx = N / 32;
    int bx = (tt % tilesx) * 32;
    int by = (tt / tilesx) * 32;
    int tx = threadIdx.x & 31, ty = threadIdx.x >> 5;
#pragma unroll
    for (int i = 0; i < 32; i += 8) {
      size_t idx = (size_t)(by + ty + i) * N + (bx + tx);
      tile[ty + i][tx] = f32 ? __float2bfloat16(((const float*)in)[idx])
                             : ((const bf16*)in)[idx];
    }
    __syncthreads();
#pragma unroll
    for (int i = 0; i < 32; i += 8)
      out[(size_t)(bx + ty + i) * K + (by + tx)] = tile[tx][ty + i];
    return;
  }
  b -= 2176;
  if (b < xbBlocks) {
    int e = (b * 256 + threadIdx.x) * 8;
    if (f32) {
      const float* src = (const float*)X + e;
      short8 r;
#pragma unroll
      for (int k = 0; k < 8; k++)
        r[k] = (short)__bfloat16_as_ushort(__float2bfloat16(src[k]));
      *(short8*)(Xb + e) = r;
    } else {
      *(short8*)(Xb + e) = *(const short8*)((const bf16*)X + e);
    }
    return;
  }
  b -= xbBlocks;
  if (b < 20) {
    auto cv = [&](const void* p, int i) -> float {
      return f32 ? ((const float*)p)[i] : __bfloat162float(((const bf16*)p)[i]);
    };
    int t = b * 256 + threadIdx.x;
    if (t < 1024) ob11[t] = cv(b11, t);
    else if (t < 2048) ob12[t - 1024] = cv(b12, t - 1024);
    else if (t < 2560) ob21[t - 2048] = cv(b21, t - 2048);
    else if (t < 3072) ob22[t - 2560] = cv(b22, t - 2560);
    else if (t < 3200) ob31[t - 3072] = cv(b31, t - 3072);
    else if (t < 3328) ob32[t - 3200] = cv(b32, t - 3200);
    else if (t < 4992) {
      int j = t - 3328;
      const void* src; float* dst; int jj;
      if (j < 1024)      { src = aw1; dst = ow1; jj = j; }
      else if (j < 1536) { src = aw2; dst = ow2; jj = j - 1024; }
      else               { src = aw3; dst = ow3; jj = j - 1536; }
      float e0 = cv(src, 2 * jj), e1 = cv(src, 2 * jj + 1);
      float mx = fmaxf(e0, e1);
      float w0 = expf(e0 - mx), w1 = expf(e1 - mx);
      float inv = 1.f / (w0 + w1);
      dst[2 * jj] = w0 * inv;
      dst[2 * jj + 1] = w1 * inv;
    }
    return;
  }
  b -= 20;
  {
    int e = b * 256 + threadIdx.x;
    if (e < E1) atomicAdd(&deg1[dst1[e]], 1);
    else if (e < E1 + E2) atomicAdd(&deg2[dst2[e - E1]], 1);
  }
}

// ---------------------------------------------------------------- scan (wave-shuffle)
__global__ void scan2_kernel(const int* __restrict__ deg1, int* __restrict__ off1,
                             float* __restrict__ dinv1,
                             const int* __restrict__ deg2, int* __restrict__ off2,
                             float* __restrict__ dinv2, int n) {
  const int* deg = blockIdx.x ? deg2 : deg1;
  int* off = blockIdx.x ? off2 : off1;
  float* dinv = blockIdx.x ? dinv2 : dinv1;
  __shared__ int wsum[16];
  __shared__ int carry_s;
  const int t = threadIdx.x;
  const int waveid = t >> 6;
  const int lane = t & 63;
  if (t == 0) carry_s = 0;
  __syncthreads();
  for (int base = 0; base < n; base += 1024) {
    int i = base + t;
    int orig = (i < n) ? deg[i] : 0;
    int v = orig;
#pragma unroll
    for (int d = 1; d < 64; d <<= 1) {
      int u = __shfl_up(v, d, 64);
      if (lane >= d) v += u;
    }
    if (lane == 63) wsum[waveid] = v;
    __syncthreads();
    if (waveid == 0 && lane < 16) {
      int s = wsum[lane];
#pragma unroll
      for (int d = 1; d < 16; d <<= 1) {
        int u = __shfl_up(s, d, 64);
        if (lane >= d) s += u;
      }
      wsum[lane] = s;
    }
    __syncthreads();
    int woff = waveid ? wsum[waveid - 1] : 0;
    int incl = v + woff;
    int carry = carry_s;
    if (i < n) {
      off[i]  = carry + incl - orig;
      dinv[i] = rsqrtf((float)(orig + 1));
    }
    __syncthreads();
    if (t == 1023) carry_s = carry + wsum[15];
    __syncthreads();
  }
  if (t == 0) off[n] = carry_s;
}

__global__ void csr_fused(const int* __restrict__ src1, const int* __restrict__ dst1, int E1,
                          const int* __restrict__ src2, const int* __restrict__ dst2, int E2,
                          const int* __restrict__ off1, int* __restrict__ cur1,
                          const float* __restrict__ dinv1,
                          int* __restrict__ cs1, float* __restrict__ cw1,
                          const int* __restrict__ off2, int* __restrict__ cur2,
                          const float* __restrict__ dinv2,
                          int* __restrict__ cs2, float* __restrict__ cw2) {
  int e = blockIdx.x * 256 + threadIdx.x;
  if (e < E1) {
    int d = dst1[e], s = src1[e];
    int slot = off1[d] + atomicAdd(&cur1[d], 1);
    cs1[slot] = s;
    cw1[slot] = dinv1[s];
  } else if (e < E1 + E2) {
    int ee = e - E1;
    int d = dst2[ee], s = src2[ee];
    int slot = off2[d] + atomicAdd(&cur2[d], 1);
    cs2[slot] = s;
    cw2[slot] = dinv2[s];
  }
}

// ---------------------------------------------------------------- gather loop (8/4/2/1 unroll)
template <int LD>
__device__ inline void gather_accum(const bf16* __restrict__ base,
                                    const int* __restrict__ cs, const float* __restrict__ cw,
                                    int s, int e, float* acc) {
  int i = s;
  for (; i + 8 <= e; i += 8) {
    short8 r[8]; float w[8];
#pragma unroll
    for (int k = 0; k < 8; k++) {
      r[k] = *(const short8*)(base + (size_t)cs[i + k] * LD);
      w[k] = cw[i + k];
    }
#pragma unroll
    for (int k = 0; k < 8; k++) bf16x8_fma(r[k], w[k], acc);
  }
  for (; i + 4 <= e; i += 4) {
    short8 r[4]; float w[4];
#pragma unroll
    for (int k = 0; k < 4; k++) {
      r[k] = *(const short8*)(base + (size_t)cs[i + k] * LD);
      w[k] = cw[i + k];
    }
#pragma unroll
    for (int k = 0; k < 4; k++) bf16x8_fma(r[k], w[k], acc);
  }
  for (; i + 2 <= e; i += 2) {
    short8 r0 = *(const short8*)(base + (size_t)cs[i] * LD);
    short8 r1 = *(const short8*)(base + (size_t)cs[i + 1] * LD);
    bf16x8_fma(r0, cw[i], acc);
    bf16x8_fma(r1, cw[i + 1], acc);
  }
  if (i < e) {
    short8 r0 = *(const short8*)(base + (size_t)cs[i] * LD);
    bf16x8_fma(r0, cw[i], acc);
  }
}

// ---------------------------------------------------------------- input-side agg (layer 1)
__global__ __launch_bounds__(256) void aggx_kernel(
    const bf16* __restrict__ X,
    const int* __restrict__ off1, const int* __restrict__ cs1, const float* __restrict__ cw1,
    const int* __restrict__ off2, const int* __restrict__ cs2, const float* __restrict__ cw2,
    const float* __restrict__ dinv1, const float* __restrict__ dinv2,
    bf16* __restrict__ outA, bf16* __restrict__ outB, int n) {
  const int lin = blockIdx.x;
  const int slice = lin & 7;
  const int vg = lin >> 3;
  const int t = threadIdx.x;
  const int v = vg * 32 + t / 8;
  if (v >= n) return;
  const int c = slice * 64 + (t & 7) * 8;
  const bf16* __restrict__ base = X + c;

  float a[8], b[8];
#pragma unroll
  for (int k = 0; k < 8; k++) { a[k] = 0.f; b[k] = 0.f; }

  gather_accum<512>(base, cs1, cw1, off1[v], off1[v + 1], a);
  gather_accum<512>(base, cs2, cw2, off2[v], off2[v + 1], b);

  short8 self = *(const short8*)(base + (size_t)v * 512);
  const float dv1 = dinv1[v], dv2 = dinv2[v];
  short8 ra, rb;
#pragma unroll
  for (int k = 0; k < 8; k++) {
    float xs = bf2f((unsigned short)self[k]);
    ra[k] = (short)__bfloat16_as_ushort(__float2bfloat16(dv1 * a[k] + dv1 * dv1 * xs));
    rb[k] = (short)__bfloat16_as_ushort(__float2bfloat16(dv2 * b[k] + dv2 * dv2 * xs));
  }
  *(short8*)(outA + (size_t)v * 512 + c) = ra;
  *(short8*)(outB + (size_t)v * 512 + c) = rb;
}

// ---------------------------------------------------------------- GEMM, BK=64, XOR-swizzled LDS
// Row = 64 elems = 128 B = 8 x 16B chunks. Store: lane loads global chunk
// (lane&7)^(lane>>3) into LDS position (lane&7) of row (lane>>3) -> pos q of
// row r holds global chunk q^(r&7). Read: global chunk g=(ks>>3)+quad at
// q=g^(l16&7) -> 8 distinct bank groups over 16 lanes = 2-way = free (m136).
__device__ inline void gemm_body(const bf16* __restrict__ A, const bf16* __restrict__ Bt,
                                 bf16* __restrict__ C, int M, int K, int N,
                                 int m0, int n0) {
  __shared__ bf16 As[128 * 64];
  __shared__ bf16 Bs[128 * 64];
  const int tid = threadIdx.x;
  const int wave = tid >> 6;
  const int lane = tid & 63;
  const int quad = lane >> 4;
  const int l16 = lane & 15;
  const int wr = (wave >> 1) * 64;
  const int wc = (wave & 1) * 64;
  const int r8 = lane >> 3;                                  // 0..7 row within portion
  const int cb = (((lane & 7) ^ (lane >> 3)) * 16);          // swizzled source chunk
  const int rq = l16 & 7;                                    // read-side row phase

  floatx4 acc[4][4];
#pragma unroll
  for (int i = 0; i < 4; i++)
#pragma unroll
    for (int j = 0; j < 4; j++) acc[i][j] = (floatx4){0.f, 0.f, 0.f, 0.f};

  for (int k0 = 0; k0 < K; k0 += 64) {
    __syncthreads();
#pragma unroll
    for (int j = 0; j < 4; ++j) {
      int p = wave * 4 + j;                                  // portion 0..15 (8 rows each)
      int ra = p * 8 + r8;
      int grow = m0 + ra; if (grow >= M) grow = M - 1;
      gl_lds16((const char*)(A + (size_t)grow * K + k0) + cb, (char*)As + p * 1024);
      int rb = n0 + p * 8 + r8;                              // N % 128 == 0, no guard
      gl_lds16((const char*)(Bt + (size_t)rb * K + k0) + cb, (char*)Bs + p * 1024);
    }
    __syncthreads();

#pragma unroll
    for (int ks = 0; ks < 2; ks++) {
      const int g = ks * 4 + quad;
      const int q = g ^ rq;
      short8 af[4], bfr[4];
#pragma unroll
      for (int i = 0; i < 4; i++)
        af[i] = *(const short8*)(As + (wr + i * 16 + l16) * 64 + q * 8);
#pragma unroll
      for (int j = 0; j < 4; j++)
        bfr[j] = *(const short8*)(Bs + (wc + j * 16 + l16) * 64 + q * 8);
#pragma unroll
      for (int i = 0; i < 4; i++)
#pragma unroll
        for (int j = 0; j < 4; j++)
          acc[i][j] = __builtin_amdgcn_mfma_f32_16x16x32_bf16(af[i], bfr[j], acc[i][j], 0, 0, 0);
    }
  }

#pragma unroll
  for (int i = 0; i < 4; i++) {
#pragma unroll
    for (int r = 0; r < 4; r++) {
      int row = m0 + wr + i * 16 + quad * 4 + r;
      if (row < M) {
#pragma unroll
        for (int j = 0; j < 4; j++) {
          int col = n0 + wc + j * 16 + l16;
          C[(size_t)row * N + col] = __float2bfloat16(acc[i][j][r]);
        }
      }
    }
  }
}

__global__ __launch_bounds__(256) void gemm128_sw(
    const bf16* __restrict__ A0, const bf16* __restrict__ Bt0, bf16* __restrict__ C0,
    const bf16* __restrict__ A1, const bf16* __restrict__ Bt1, bf16* __restrict__ C1,
    int M, int K, int N, int mtilesPerHalf, int mtTotal, int ntLog2) {
  int lin = blockIdx.x;
  int g = lin & 7;
  int s = lin >> 3;
  int n_t = s & ((1 << ntLog2) - 1);
  int m_t = g + 8 * (s >> ntLog2);
  if (m_t >= mtTotal) return;
  int half = (m_t >= mtilesPerHalf) ? 1 : 0;
  int m_local = m_t - half * mtilesPerHalf;
  const bf16* A = half ? A1 : A0;
  const bf16* Bt = half ? Bt1 : Bt0;
  bf16* C = half ? C1 : C0;
  gemm_body(A, Bt, C, M, K, N, m_local * 128, n_t * 128);
}

// ---------------------------------------------------------------- layer-1 fused GEMM
// 512 threads, 128x128 tile, both GEMMs, BK=32 (4 buffers would hit 64KB at BK=64).
__global__ __launch_bounds__(512, 4) void gemm_l1f(
    const bf16* __restrict__ Aa, const bf16* __restrict__ Bta,
    const bf16* __restrict__ Ab, const bf16* __restrict__ Btb,
    const float* __restrict__ ba, const float* __restrict__ bb,
    const float* __restrict__ w01, bf16* __restrict__ out,
    int M, int K, int N, int mtiles) {
  int lin = blockIdx.x;
  int g = lin & 7;
  int s = lin >> 3;
  int n_t = s & 7;
  int m_t = g + 8 * (s >> 3);
  if (m_t >= mtiles) return;
  const int m0 = m_t * 128, n0 = n_t * 128;

  __shared__ bf16 Asa[128 * 32];
  __shared__ bf16 Asb[128 * 32];
  __shared__ bf16 Bsa[128 * 32];
  __shared__ bf16 Bsb[128 * 32];
  const int tid = threadIdx.x;
  const int wave = tid >> 6;        // 0..7
  const int lane = tid & 63;
  const int quad = lane >> 4;
  const int l16 = lane & 15;
  const int wr = (wave >> 2) * 64;  // 0,64
  const int wc = (wave & 3) * 32;   // 0,32,64,96
  const int r_sub = lane >> 2;
  const int cb = (((lane & 3) ^ ((lane >> 3) & 3)) * 16);
  const int rsw = (l16 >> 1) & 3;

  const int buf = wave >> 1;        // 0:Asa 1:Asb 2:Bsa 3:Bsb
  const bf16* gsrc = (buf == 0) ? Aa : (buf == 1) ? Ab : (buf == 2) ? Bta : Btb;
  bf16* lds = (buf == 0) ? Asa : (buf == 1) ? Asb : (buf == 2) ? Bsa : Bsb;
  const int base_row = (buf < 2) ? m0 : n0;
  const bool isA = (buf < 2);

  floatx4 acca[4][2], accb[4][2];
#pragma unroll
  for (int i = 0; i < 4; i++)
#pragma unroll
    for (int j = 0; j < 2; j++) {
      acca[i][j] = (floatx4){0.f, 0.f, 0.f, 0.f};
      accb[i][j] = (floatx4){0.f, 0.f, 0.f, 0.f};
    }

  for (int k0 = 0; k0 < K; k0 += 32) {
    __syncthreads();
#pragma unroll
    for (int j = 0; j < 4; ++j) {
      int pr = (wave & 1) * 4 + j;
      int row = pr * 16 + r_sub;
      int grow = base_row + row;
      if (isA && grow >= M) grow = M - 1;
      gl_lds16((const char*)(gsrc + (size_t)grow * K + k0) + cb, (char*)lds + pr * 1024);
    }
    __syncthreads();

    short8 afa[4], afb[4], bfa[2], bfb[2];
#pragma unroll
    for (int i = 0; i < 4; i++) {
      afa[i] = *(const short8*)(Asa + (wr + i * 16 + l16) * 32 + (quad ^ rsw) * 8);
      afb[i] = *(const short8*)(Asb + (wr + i * 16 + l16) * 32 + (quad ^ rsw) * 8);
    }
#pragma unroll
    for (int j = 0; j < 2; j++) {
      bfa[j] = *(const short8*)(Bsa + (wc + j * 16 + l16) * 32 + (quad ^ rsw) * 8);
      bfb[j] = *(const short8*)(Bsb + (wc + j * 16 + l16) * 32 + (quad ^ rsw) * 8);
    }
#pragma unroll
    for (int i = 0; i < 4; i++)
#pragma unroll
      for (int j = 0; j < 2; j++) {
        acca[i][j] = __builtin_amdgcn_mfma_f32_16x16x32_bf16(afa[i], bfa[j], acca[i][j], 0, 0, 0);
        accb[i][j] = __builtin_amdgcn_mfma_f32_16x16x32_bf16(afb[i], bfb[j], accb[i][j], 0, 0, 0);
      }
  }

#pragma unroll
  for (int j = 0; j < 2; j++) {
    int col = n0 + wc + j * 16 + l16;
    float baj = ba[col], bbj = bb[col];
    float w0 = w01[2 * col], w1 = w01[2 * col + 1];
#pragma unroll
    for (int i = 0; i < 4; i++) {
#pragma unroll
      for (int r = 0; r < 4; r++) {
        int row = m0 + wr + i * 16 + quad * 4 + r;
        if (row < M) {
          float x = eluf(acca[i][j][r] + baj);
          float y = eluf(accb[i][j][r] + bbj);
          out[(size_t)row * N + col] = __float2bfloat16(x * w0 + y * w1);
        }
      }
    }
  }
}

// ---------------------------------------------------------------- layer-2 agg, XCD channel-sliced
__global__ __launch_bounds__(256) void agg2_kernel(
    const bf16* __restrict__ Ha, const bf16* __restrict__ Hb,  // ldH = 1024
    const int* __restrict__ off1, const int* __restrict__ cs1, const float* __restrict__ cw1,
    const int* __restrict__ off2, const int* __restrict__ cs2, const float* __restrict__ cw2,
    const float* __restrict__ dinv1, const float* __restrict__ dinv2,
    const float* __restrict__ ba, const float* __restrict__ bb,
    const float* __restrict__ w01, bf16* __restrict__ out, int n) {
  const int lin = blockIdx.x;
  const int slice = lin & 7;
  const int vg = lin >> 3;
  const int t = threadIdx.x;
  const int v = vg * 32 + t / 8;
  if (v >= n) return;
  const int c = slice * 64 + (t & 7) * 8;
  const bf16* __restrict__ baseA = Ha + c;
  const bf16* __restrict__ baseB = Hb + c;

  float a[8], b[8];
#pragma unroll
  for (int k = 0; k < 8; k++) { a[k] = 0.f; b[k] = 0.f; }

  gather_accum<1024>(baseA, cs1, cw1, off1[v], off1[v + 1], a);
  gather_accum<1024>(baseB, cs2, cw2, off2[v], off2[v + 1], b);

  short8 sa = *(const short8*)(baseA + (size_t)v * 1024);
  short8 sb = *(const short8*)(baseB + (size_t)v * 1024);
  const float dv1 = dinv1[v], dv2 = dinv2[v];

  short8 r;
#pragma unroll
  for (int k = 0; k < 8; k++) {
    float x = eluf(dv1 * a[k] + dv1 * dv1 * bf2f((unsigned short)sa[k]) + ba[c + k]);
    float y = eluf(dv2 * b[k] + dv2 * dv2 * bf2f((unsigned short)sb[k]) + bb[c + k]);
    r[k] = (short)__bfloat16_as_ushort(
        __float2bfloat16(x * w01[2 * (c + k)] + y * w01[2 * (c + k) + 1]));
  }
  *(short8*)(out + (size_t)v * 512 + c) = r;
}

// ---------------------------------------------------------------- layer-3 agg
template <int C, int LD, bool WU>
__global__ __launch_bounds__(256) void agg_out_kernel(
    const bf16* __restrict__ Ha, const bf16* __restrict__ Hb,
    const int* __restrict__ off1, const int* __restrict__ cs1, const float* __restrict__ cw1,
    const int* __restrict__ off2, const int* __restrict__ cs2, const float* __restrict__ cw2,
    const float* __restrict__ dinv1, const float* __restrict__ dinv2,
    const float* __restrict__ ba, const float* __restrict__ bb,
    const float* __restrict__ w01, void* __restrict__ out, int n,
    const int* __restrict__ outflag) {
  constexpr int TPV = C / 8;
  constexpr int G = 256 / TPV;
  const int t = threadIdx.x;
  int v = blockIdx.x * G + t / TPV;
  if (v >= n) return;
  if (WU) v = __builtin_amdgcn_readfirstlane(v);
  const int c = (t % TPV) * 8;
  const bf16* __restrict__ baseA = Ha + c;
  const bf16* __restrict__ baseB = Hb + c;

  float a[8], b[8];
#pragma unroll
  for (int k = 0; k < 8; k++) { a[k] = 0.f; b[k] = 0.f; }

  int s1 = off1[v], e1 = off1[v + 1];
  if (WU) { s1 = __builtin_amdgcn_readfirstlane(s1); e1 = __builtin_amdgcn_readfirstlane(e1); }
  gather_accum<LD>(baseA, cs1, cw1, s1, e1, a);
  int s2 = off2[v], e2 = off2[v + 1];
  if (WU) { s2 = __builtin_amdgcn_readfirstlane(s2); e2 = __builtin_amdgcn_readfirstlane(e2); }
  gather_accum<LD>(baseB, cs2, cw2, s2, e2, b);

  short8 sa = *(const short8*)(baseA + (size_t)v * LD);
  short8 sb = *(const short8*)(baseB + (size_t)v * LD);
  const float dv1 = dinv1[v], dv2 = dinv2[v];

  float r[8];
#pragma unroll
  for (int k = 0; k < 8; k++) {
    float x = eluf(dv1 * a[k] + dv1 * dv1 * bf2f((unsigned short)sa[k]) + ba[c + k]);
    float y = eluf(dv2 * b[k] + dv2 * dv2 * bf2f((unsigned short)sb[k]) + bb[c + k]);
    r[k] = x * w01[2 * (c + k)] + y * w01[2 * (c + k) + 1];
  }

  const bool out_f32 = (outflag != nullptr) && (*outflag != 0);
  size_t oi = (size_t)v * C + c;
  if (out_f32) {
    floatx4 lo = {r[0], r[1], r[2], r[3]};
    floatx4 hi = {r[4], r[5], r[6], r[7]};
    *(floatx4*)((float*)out + oi) = lo;
    *(floatx4*)((float*)out + oi + 4) = hi;
  } else {
    short8 rb;
#pragma unroll
    for (int k = 0; k < 8; k++)
      rb[k] = (short)__bfloat16_as_ushort(__float2bfloat16(r[k]));
    *(short8*)((bf16*)out + oi) = rb;
  }
}

// ---------------------------------------------------------------- host pipeline
extern "C" void kernel_launch(void* const* d_in, const int* in_sizes, int n_in,
                              void* d_out, int out_size, void* d_ws, size_t ws_size,
                              hipStream_t stream) {
  const void* X = d_in[0];
  const int* ei1 = (const int*)d_in[1];
  const int* ei2 = (const int*)d_in[2];
  const int n = in_sizes[0] / 512;
  const int E1 = in_sizes[1] / 2;
  const int E2 = in_sizes[2] / 2;
  const int* src1 = ei1;           const int* dst1 = ei1 + E1;
  const int* src2 = ei2;           const int* dst2 = ei2 + E2;

  auto rnd = [](size_t b) { return (b + 255) & ~(size_t)255; };
  char* p = (char*)d_ws;
  auto alloc = [&](size_t bytes) { char* r = p; p += rnd(bytes); return r; };

  int* flag = (int*)alloc(256);
  int* deg1 = (int*)alloc((size_t)n * 4);
  int* deg2 = (int*)alloc((size_t)n * 4);
  int* cur1 = (int*)alloc((size_t)n * 4);
  int* cur2 = (int*)alloc((size_t)n * 4);
  int* off1 = (int*)alloc((size_t)(n + 1) * 4);
  int* off2 = (int*)alloc((size_t)(n + 1) * 4);
  float* dinv1 = (float*)alloc((size_t)n * 4);
  float* dinv2 = (float*)alloc((size_t)n * 4);
  int* cs1 = (int*)alloc((size_t)E1 * 4);
  float* cw1 = (float*)alloc((size_t)E1 * 4);
  int* cs2 = (int*)alloc((size_t)E2 * 4);
  float* cw2 = (float*)alloc((size_t)E2 * 4);
  bf16* Wt11 = (bf16*)alloc((size_t)512 * 1024 * 2);
  bf16* Wt12 = (bf16*)alloc((size_t)512 * 1024 * 2);
  bf16* Wt2cat = (bf16*)alloc((size_t)1024 * 1024 * 2);
  bf16* Wt3cat = (bf16*)alloc((size_t)256 * 512 * 2);
  float* bf_[6]; int bsz[6] = {1024, 1024, 512, 512, 128, 128};
  for (int i = 0; i < 6; i++) bf_[i] = (float*)alloc((size_t)bsz[i] * 4);
  float* w01_[3]; int asz[3] = {2048, 1024, 256};
  for (int i = 0; i < 3; i++) w01_[i] = (float*)alloc((size_t)asz[i] * 4);
  bf16* Xb = (bf16*)alloc((size_t)n * 512 * 2);
  bf16* aggXa = (bf16*)alloc((size_t)n * 512 * 2);
  bf16* aggXb = (bf16*)alloc((size_t)n * 512 * 2);
  bf16* H1a = (bf16*)alloc((size_t)n * 1024 * 2);
  bf16* act1 = (bf16*)alloc((size_t)n * 1024 * 2);
  bf16* H2cat = H1a;
  bf16* act2 = aggXa;  // dead after gemm_l1f
  bf16* H3cat = aggXb; // dead after gemm_l1f

  // ---- prep: probe + zero counters
  int zwords = (int)(rnd((size_t)n * 4) * 4 / 4);
  probe_zero<<<1 + (zwords + 1023) / 1024, 256, 0, stream>>>(
      (const unsigned short*)X, flag, deg1, zwords);

  // ---- fused prep
  int xbBlocks = (n * 512) / 2048;
  int degBlocks = (E1 + E2 + 255) / 256;
  prep_all<<<2176 + xbBlocks + 20 + degBlocks, 256, 0, stream>>>(
      X, Xb, n * 512,
      d_in[3], d_in[5], d_in[7], d_in[9], d_in[11], d_in[13],
      Wt11, Wt12, Wt2cat, Wt3cat,
      d_in[4], d_in[6], d_in[8], d_in[10], d_in[12], d_in[14],
      d_in[15], d_in[16], d_in[17],
      bf_[0], bf_[1], bf_[2], bf_[3], bf_[4], bf_[5],
      w01_[0], w01_[1], w01_[2],
      dst1, E1, dst2, E2, deg1, deg2, flag);

  scan2_kernel<<<2, 1024, 0, stream>>>(deg1, off1, dinv1, deg2, off2, dinv2, n);
  csr_fused<<<(E1 + E2 + 255) / 256, 256, 0, stream>>>(src1, dst1, E1, src2, dst2, E2,
                                                       off1, cur1, dinv1, cs1, cw1,
                                                       off2, cur2, dinv2, cs2, cw2);

  const int mtiles = (n + 127) / 128;
  auto swgrid = [](int mtTotal, int ntiles) {
    return 8 * ntiles * ((mtTotal + 7) / 8);
  };
  const int vg32 = 8 * ((n + 31) / 32);
  // ---- layer 1
  aggx_kernel<<<vg32, 256, 0, stream>>>(Xb, off1, cs1, cw1, off2, cs2, cw2,
                                        dinv1, dinv2, aggXa, aggXb, n);
  gemm_l1f<<<swgrid(mtiles, 8), 512, 0, stream>>>(
      aggXa, Wt11, aggXb, Wt12, bf_[0], bf_[1], w01_[0], act1, n, 512, 1024, mtiles);
  // ---- layer 2 (BK=64 GEMM)
  gemm128_sw<<<swgrid(mtiles, 8), 256, 0, stream>>>(
      act1, Wt2cat, H2cat, act1, Wt2cat, H2cat, n, 1024, 1024, mtiles, mtiles, 3);
  agg2_kernel<<<vg32, 256, 0, stream>>>(H2cat, H2cat + 512,
                                        off1, cs1, cw1, off2, cs2, cw2,
                                        dinv1, dinv2, bf_[2], bf_[3], w01_[1], act2, n);
  // ---- layer 3 (BK=64 GEMM)
  gemm128_sw<<<swgrid(mtiles, 2), 256, 0, stream>>>(
      act2, Wt3cat, H3cat, act2, Wt3cat, H3cat, n, 512, 256, mtiles, mtiles, 1);
  agg_out_kernel<128, 256, false><<<(n + 15) / 16, 256, 0, stream>>>(
      H3cat, H3cat + 128, off1, cs1, cw1, off2, cs2, cw2,
      dinv1, dinv2, bf_[4], bf_[5], w01_[2], d_out, n, flag);
}

// Round 15
// 300.981 us; speedup vs baseline: 1.0417x; 1.0157x over previous
//
#include <hip/hip_runtime.h>
#include <hip/hip_bf16.h>
#include <math.h>

using bf16 = __hip_bfloat16;
typedef __attribute__((ext_vector_type(8))) short short8;
typedef __attribute__((ext_vector_type(4))) float floatx4;

// ---------------------------------------------------------------- helpers
__device__ inline void gl_lds16(const void* g, void* l) {
  __builtin_amdgcn_global_load_lds(
      (const __attribute__((address_space(1))) unsigned int*)g,
      (__attribute__((address_space(3))) unsigned int*)l,
      16, 0, 0);
}
__device__ inline float eluf(float x) { return x > 0.f ? x : __expf(x) - 1.f; }
__device__ inline float bf2f(unsigned short h) {
  return __uint_as_float(((unsigned)h) << 16);
}
__device__ inline void bf16x8_fma(short8 r, float w, float* acc) {
#pragma unroll
  for (int k = 0; k < 8; k++) acc[k] += w * bf2f((unsigned short)r[k]);
}

// ---------------------------------------------------------------- probe + zero counters
__global__ void probe_zero(const unsigned short* __restrict__ x, int* __restrict__ flag,
                           int* __restrict__ zbase, int zwords) {
  if (blockIdx.x == 0) {
    __shared__ int s;
    int t = threadIdx.x;
    if (t == 0) s = 0;
    __syncthreads();
    int bad = 0;
    for (int i = t; i < 1024; i += 256) {
      unsigned short h = x[2 * i];
      unsigned e = (h >> 7) & 0xFF;
      if (e >= 0xE5) bad = 1;
    }
    if (bad) atomicOr(&s, 1);
    __syncthreads();
    if (t == 0) flag[0] = s;
  } else {
    int i = (blockIdx.x - 1) * 1024 + threadIdx.x * 4;
    if (i < zwords) {
      zbase[i] = 0; zbase[i + 1] = 0; zbase[i + 2] = 0; zbase[i + 3] = 0;
    }
  }
}

// ---------------------------------------------------------------- fused prep
__global__ void prep_all(
    const void* X, bf16* __restrict__ Xb, int nx,
    const void* W11, const void* W12, const void* W21, const void* W22,
    const void* W31, const void* W32,
    bf16* Wt11, bf16* Wt12, bf16* Wt2cat, bf16* Wt3cat,
    const void* b11, const void* b12, const void* b21, const void* b22,
    const void* b31, const void* b32, const void* aw1, const void* aw2, const void* aw3,
    float* ob11, float* ob12, float* ob21, float* ob22, float* ob31, float* ob32,
    float* ow1, float* ow2, float* ow3,
    const int* __restrict__ dst1, int E1, const int* __restrict__ dst2, int E2,
    int* __restrict__ deg1, int* __restrict__ deg2,
    const int* __restrict__ flag) {
  const bool f32 = *flag != 0;
  int b = blockIdx.x;
  const int xbBlocks = nx / 2048;
  if (b < 2176) {
    __shared__ bf16 tile[32][33];
    const void* in; bf16* out; int K, N, tt;
    if (b < 512)       { in = W11; out = Wt11; K = 512;  N = 1024; tt = b; }
    else if (b < 1024) { in = W12; out = Wt12; K = 512;  N = 1024; tt = b - 512; }
    else if (b < 1536) { in = W21; out = Wt2cat; K = 1024; N = 512; tt = b - 1024; }
    else if (b < 2048) { in = W22; out = Wt2cat + (size_t)512 * 1024; K = 1024; N = 512; tt = b - 1536; }
    else if (b < 2112) { in = W31; out = Wt3cat; K = 512; N = 128; tt = b - 2048; }
    else               { in = W32; out = Wt3cat + (size_t)128 * 512; K = 512; N = 128; tt = b - 2112; }
    int tilesx = N / 32;
    int bx = (tt % tilesx) * 32;
    int by = (tt / tilesx) * 32;
    int tx = threadIdx.x & 31, ty = threadIdx.x >> 5;
#pragma unroll
    for (int i = 0; i < 32; i += 8) {
      size_t idx = (size_t)(by + ty + i) * N + (bx + tx);
      tile[ty + i][tx] = f32 ? __float2bfloat16(((const float*)in)[idx])
                             : ((const bf16*)in)[idx];
    }
    __syncthreads();
#pragma unroll
    for (int i = 0; i < 32; i += 8)
      out[(size_t)(bx + ty + i) * K + (by + tx)] = tile[tx][ty + i];
    return;
  }
  b -= 2176;
  if (b < xbBlocks) {
    int e = (b * 256 + threadIdx.x) * 8;
    if (f32) {
      const float* src = (const float*)X + e;
      short8 r;
#pragma unroll
      for (int k = 0; k < 8; k++)
        r[k] = (short)__bfloat16_as_ushort(__float2bfloat16(src[k]));
      *(short8*)(Xb + e) = r;
    } else {
      *(short8*)(Xb + e) = *(const short8*)((const bf16*)X + e);
    }
    return;
  }
  b -= xbBlocks;
  if (b < 20) {
    auto cv = [&](const void* p, int i) -> float {
      return f32 ? ((const float*)p)[i] : __bfloat162float(((const bf16*)p)[i]);
    };
    int t = b * 256 + threadIdx.x;
    if (t < 1024) ob11[t] = cv(b11, t);
    else if (t < 2048) ob12[t - 1024] = cv(b12, t - 1024);
    else if (t < 2560) ob21[t - 2048] = cv(b21, t - 2048);
    else if (t < 3072) ob22[t - 2560] = cv(b22, t - 2560);
    else if (t < 3200) ob31[t - 3072] = cv(b31, t - 3072);
    else if (t < 3328) ob32[t - 3200] = cv(b32, t - 3200);
    else if (t < 4992) {
      int j = t - 3328;
      const void* src; float* dst; int jj;
      if (j < 1024)      { src = aw1; dst = ow1; jj = j; }
      else if (j < 1536) { src = aw2; dst = ow2; jj = j - 1024; }
      else               { src = aw3; dst = ow3; jj = j - 1536; }
      float e0 = cv(src, 2 * jj), e1 = cv(src, 2 * jj + 1);
      float mx = fmaxf(e0, e1);
      float w0 = expf(e0 - mx), w1 = expf(e1 - mx);
      float inv = 1.f / (w0 + w1);
      dst[2 * jj] = w0 * inv;
      dst[2 * jj + 1] = w1 * inv;
    }
    return;
  }
  b -= 20;
  {
    int e = b * 256 + threadIdx.x;
    if (e < E1) atomicAdd(&deg1[dst1[e]], 1);
    else if (e < E1 + E2) atomicAdd(&deg2[dst2[e - E1]], 1);
  }
}

// ---------------------------------------------------------------- scan (wave-shuffle)
__global__ void scan2_kernel(const int* __restrict__ deg1, int* __restrict__ off1,
                             float* __restrict__ dinv1,
                             const int* __restrict__ deg2, int* __restrict__ off2,
                             float* __restrict__ dinv2, int n) {
  const int* deg = blockIdx.x ? deg2 : deg1;
  int* off = blockIdx.x ? off2 : off1;
  float* dinv = blockIdx.x ? dinv2 : dinv1;
  __shared__ int wsum[16];
  __shared__ int carry_s;
  const int t = threadIdx.x;
  const int waveid = t >> 6;
  const int lane = t & 63;
  if (t == 0) carry_s = 0;
  __syncthreads();
  for (int base = 0; base < n; base += 1024) {
    int i = base + t;
    int orig = (i < n) ? deg[i] : 0;
    int v = orig;
#pragma unroll
    for (int d = 1; d < 64; d <<= 1) {
      int u = __shfl_up(v, d, 64);
      if (lane >= d) v += u;
    }
    if (lane == 63) wsum[waveid] = v;
    __syncthreads();
    if (waveid == 0 && lane < 16) {
      int s = wsum[lane];
#pragma unroll
      for (int d = 1; d < 16; d <<= 1) {
        int u = __shfl_up(s, d, 64);
        if (lane >= d) s += u;
      }
      wsum[lane] = s;
    }
    __syncthreads();
    int woff = waveid ? wsum[waveid - 1] : 0;
    int incl = v + woff;
    int carry = carry_s;
    if (i < n) {
      off[i]  = carry + incl - orig;
      dinv[i] = rsqrtf((float)(orig + 1));
    }
    __syncthreads();
    if (t == 1023) carry_s = carry + wsum[15];
    __syncthreads();
  }
  if (t == 0) off[n] = carry_s;
}

__global__ void csr_fused(const int* __restrict__ src1, const int* __restrict__ dst1, int E1,
                          const int* __restrict__ src2, const int* __restrict__ dst2, int E2,
                          const int* __restrict__ off1, int* __restrict__ cur1,
                          const float* __restrict__ dinv1,
                          int* __restrict__ cs1, float* __restrict__ cw1,
                          const int* __restrict__ off2, int* __restrict__ cur2,
                          const float* __restrict__ dinv2,
                          int* __restrict__ cs2, float* __restrict__ cw2) {
  int e = blockIdx.x * 256 + threadIdx.x;
  if (e < E1) {
    int d = dst1[e], s = src1[e];
    int slot = off1[d] + atomicAdd(&cur1[d], 1);
    cs1[slot] = s;
    cw1[slot] = dinv1[s];
  } else if (e < E1 + E2) {
    int ee = e - E1;
    int d = dst2[ee], s = src2[ee];
    int slot = off2[d] + atomicAdd(&cur2[d], 1);
    cs2[slot] = s;
    cw2[slot] = dinv2[s];
  }
}

// ---------------------------------------------------------------- gather loop (8/4/2/1 unroll)
template <int LD>
__device__ inline void gather_accum(const bf16* __restrict__ base,
                                    const int* __restrict__ cs, const float* __restrict__ cw,
                                    int s, int e, float* acc) {
  int i = s;
  for (; i + 8 <= e; i += 8) {
    short8 r[8]; float w[8];
#pragma unroll
    for (int k = 0; k < 8; k++) {
      r[k] = *(const short8*)(base + (size_t)cs[i + k] * LD);
      w[k] = cw[i + k];
    }
#pragma unroll
    for (int k = 0; k < 8; k++) bf16x8_fma(r[k], w[k], acc);
  }
  for (; i + 4 <= e; i += 4) {
    short8 r[4]; float w[4];
#pragma unroll
    for (int k = 0; k < 4; k++) {
      r[k] = *(const short8*)(base + (size_t)cs[i + k] * LD);
      w[k] = cw[i + k];
    }
#pragma unroll
    for (int k = 0; k < 4; k++) bf16x8_fma(r[k], w[k], acc);
  }
  for (; i + 2 <= e; i += 2) {
    short8 r0 = *(const short8*)(base + (size_t)cs[i] * LD);
    short8 r1 = *(const short8*)(base + (size_t)cs[i + 1] * LD);
    bf16x8_fma(r0, cw[i], acc);
    bf16x8_fma(r1, cw[i + 1], acc);
  }
  if (i < e) {
    short8 r0 = *(const short8*)(base + (size_t)cs[i] * LD);
    bf16x8_fma(r0, cw[i], acc);
  }
}

// ---------------------------------------------------------------- input-side agg (layer 1)
__global__ __launch_bounds__(256) void aggx_kernel(
    const bf16* __restrict__ X,
    const int* __restrict__ off1, const int* __restrict__ cs1, const float* __restrict__ cw1,
    const int* __restrict__ off2, const int* __restrict__ cs2, const float* __restrict__ cw2,
    const float* __restrict__ dinv1, const float* __restrict__ dinv2,
    bf16* __restrict__ outA, bf16* __restrict__ outB, int n) {
  const int lin = blockIdx.x;
  const int slice = lin & 7;
  const int vg = lin >> 3;
  const int t = threadIdx.x;
  const int v = vg * 32 + t / 8;
  if (v >= n) return;
  const int c = slice * 64 + (t & 7) * 8;
  const bf16* __restrict__ base = X + c;

  float a[8], b[8];
#pragma unroll
  for (int k = 0; k < 8; k++) { a[k] = 0.f; b[k] = 0.f; }

  gather_accum<512>(base, cs1, cw1, off1[v], off1[v + 1], a);
  gather_accum<512>(base, cs2, cw2, off2[v], off2[v + 1], b);

  short8 self = *(const short8*)(base + (size_t)v * 512);
  const float dv1 = dinv1[v], dv2 = dinv2[v];
  short8 ra, rb;
#pragma unroll
  for (int k = 0; k < 8; k++) {
    float xs = bf2f((unsigned short)self[k]);
    ra[k] = (short)__bfloat16_as_ushort(__float2bfloat16(dv1 * a[k] + dv1 * dv1 * xs));
    rb[k] = (short)__bfloat16_as_ushort(__float2bfloat16(dv2 * b[k] + dv2 * dv2 * xs));
  }
  *(short8*)(outA + (size_t)v * 512 + c) = ra;
  *(short8*)(outB + (size_t)v * 512 + c) = rb;
}

// ---------------------------------------------------------------- GEMM, BK=64, XOR-swizzled LDS
__device__ inline void gemm_body(const bf16* __restrict__ A, const bf16* __restrict__ Bt,
                                 bf16* __restrict__ C, int M, int K, int N,
                                 int m0, int n0) {
  __shared__ bf16 As[128 * 64];
  __shared__ bf16 Bs[128 * 64];
  const int tid = threadIdx.x;
  const int wave = tid >> 6;
  const int lane = tid & 63;
  const int quad = lane >> 4;
  const int l16 = lane & 15;
  const int wr = (wave >> 1) * 64;
  const int wc = (wave & 1) * 64;
  const int r8 = lane >> 3;
  const int cb = (((lane & 7) ^ (lane >> 3)) * 16);
  const int rq = l16 & 7;

  floatx4 acc[4][4];
#pragma unroll
  for (int i = 0; i < 4; i++)
#pragma unroll
    for (int j = 0; j < 4; j++) acc[i][j] = (floatx4){0.f, 0.f, 0.f, 0.f};

  for (int k0 = 0; k0 < K; k0 += 64) {
    __syncthreads();
#pragma unroll
    for (int j = 0; j < 4; ++j) {
      int p = wave * 4 + j;
      int ra = p * 8 + r8;
      int grow = m0 + ra; if (grow >= M) grow = M - 1;
      gl_lds16((const char*)(A + (size_t)grow * K + k0) + cb, (char*)As + p * 1024);
      int rb = n0 + p * 8 + r8;
      gl_lds16((const char*)(Bt + (size_t)rb * K + k0) + cb, (char*)Bs + p * 1024);
    }
    __syncthreads();

#pragma unroll
    for (int ks = 0; ks < 2; ks++) {
      const int g = ks * 4 + quad;
      const int q = g ^ rq;
      short8 af[4], bfr[4];
#pragma unroll
      for (int i = 0; i < 4; i++)
        af[i] = *(const short8*)(As + (wr + i * 16 + l16) * 64 + q * 8);
#pragma unroll
      for (int j = 0; j < 4; j++)
        bfr[j] = *(const short8*)(Bs + (wc + j * 16 + l16) * 64 + q * 8);
#pragma unroll
      for (int i = 0; i < 4; i++)
#pragma unroll
        for (int j = 0; j < 4; j++)
          acc[i][j] = __builtin_amdgcn_mfma_f32_16x16x32_bf16(af[i], bfr[j], acc[i][j], 0, 0, 0);
    }
  }

#pragma unroll
  for (int i = 0; i < 4; i++) {
#pragma unroll
    for (int r = 0; r < 4; r++) {
      int row = m0 + wr + i * 16 + quad * 4 + r;
      if (row < M) {
#pragma unroll
        for (int j = 0; j < 4; j++) {
          int col = n0 + wc + j * 16 + l16;
          C[(size_t)row * N + col] = __float2bfloat16(acc[i][j][r]);
        }
      }
    }
  }
}

__global__ __launch_bounds__(256) void gemm128_sw(
    const bf16* __restrict__ A0, const bf16* __restrict__ Bt0, bf16* __restrict__ C0,
    const bf16* __restrict__ A1, const bf16* __restrict__ Bt1, bf16* __restrict__ C1,
    int M, int K, int N, int mtilesPerHalf, int mtTotal, int ntLog2) {
  int lin = blockIdx.x;
  int g = lin & 7;
  int s = lin >> 3;
  int n_t = s & ((1 << ntLog2) - 1);
  int m_t = g + 8 * (s >> ntLog2);
  if (m_t >= mtTotal) return;
  int half = (m_t >= mtilesPerHalf) ? 1 : 0;
  int m_local = m_t - half * mtilesPerHalf;
  const bf16* A = half ? A1 : A0;
  const bf16* Bt = half ? Bt1 : Bt0;
  bf16* C = half ? C1 : C0;
  gemm_body(A, Bt, C, M, K, N, m_local * 128, n_t * 128);
}

// ---------------------------------------------------------------- layer-1 fused GEMM
// 512 threads, 128x128 tile, both GEMMs, BK=64: 4 LDS buffers x 16 KB = 64 KB.
// 2 blocks/CU (thread-limited anyway) -> barrier pairs halve vs BK=32 at equal occupancy.
__global__ __launch_bounds__(512, 4) void gemm_l1f(
    const bf16* __restrict__ Aa, const bf16* __restrict__ Bta,
    const bf16* __restrict__ Ab, const bf16* __restrict__ Btb,
    const float* __restrict__ ba, const float* __restrict__ bb,
    const float* __restrict__ w01, bf16* __restrict__ out,
    int M, int K, int N, int mtiles) {
  int lin = blockIdx.x;
  int g = lin & 7;
  int s = lin >> 3;
  int n_t = s & 7;
  int m_t = g + 8 * (s >> 3);
  if (m_t >= mtiles) return;
  const int m0 = m_t * 128, n0 = n_t * 128;

  __shared__ bf16 Asa[128 * 64];
  __shared__ bf16 Asb[128 * 64];
  __shared__ bf16 Bsa[128 * 64];
  __shared__ bf16 Bsb[128 * 64];
  const int tid = threadIdx.x;
  const int wave = tid >> 6;        // 0..7
  const int lane = tid & 63;
  const int quad = lane >> 4;
  const int l16 = lane & 15;
  const int wr = (wave >> 2) * 64;  // 0,64
  const int wc = (wave & 3) * 32;   // 0,32,64,96
  const int r8 = lane >> 3;
  const int cb = (((lane & 7) ^ (lane >> 3)) * 16);
  const int rq = l16 & 7;

  const int buf = wave >> 1;        // 0:Asa 1:Asb 2:Bsa 3:Bsb
  const bf16* gsrc = (buf == 0) ? Aa : (buf == 1) ? Ab : (buf == 2) ? Bta : Btb;
  bf16* lds = (buf == 0) ? Asa : (buf == 1) ? Asb : (buf == 2) ? Bsa : Bsb;
  const int base_row = (buf < 2) ? m0 : n0;
  const bool isA = (buf < 2);

  floatx4 acca[4][2], accb[4][2];
#pragma unroll
  for (int i = 0; i < 4; i++)
#pragma unroll
    for (int j = 0; j < 2; j++) {
      acca[i][j] = (floatx4){0.f, 0.f, 0.f, 0.f};
      accb[i][j] = (floatx4){0.f, 0.f, 0.f, 0.f};
    }

  for (int k0 = 0; k0 < K; k0 += 64) {
    __syncthreads();
#pragma unroll
    for (int j = 0; j < 8; ++j) {
      int pr = (wave & 1) * 8 + j;            // 0..15 within buffer (8 rows each)
      int row = pr * 8 + r8;
      int grow = base_row + row;
      if (isA && grow >= M) grow = M - 1;      // N multiple of 128: B unguarded
      gl_lds16((const char*)(gsrc + (size_t)grow * K + k0) + cb, (char*)lds + pr * 1024);
    }
    __syncthreads();

#pragma unroll
    for (int ks = 0; ks < 2; ks++) {
      const int g2 = ks * 4 + quad;
      const int q = g2 ^ rq;
      short8 afa[4], afb[4], bfa[2], bfb[2];
#pragma unroll
      for (int i = 0; i < 4; i++) {
        afa[i] = *(const short8*)(Asa + (wr + i * 16 + l16) * 64 + q * 8);
        afb[i] = *(const short8*)(Asb + (wr + i * 16 + l16) * 64 + q * 8);
      }
#pragma unroll
      for (int j = 0; j < 2; j++) {
        bfa[j] = *(const short8*)(Bsa + (wc + j * 16 + l16) * 64 + q * 8);
        bfb[j] = *(const short8*)(Bsb + (wc + j * 16 + l16) * 64 + q * 8);
      }
#pragma unroll
      for (int i = 0; i < 4; i++)
#pragma unroll
        for (int j = 0; j < 2; j++) {
          acca[i][j] = __builtin_amdgcn_mfma_f32_16x16x32_bf16(afa[i], bfa[j], acca[i][j], 0, 0, 0);
          accb[i][j] = __builtin_amdgcn_mfma_f32_16x16x32_bf16(afb[i], bfb[j], accb[i][j], 0, 0, 0);
        }
    }
  }

#pragma unroll
  for (int j = 0; j < 2; j++) {
    int col = n0 + wc + j * 16 + l16;
    float baj = ba[col], bbj = bb[col];
    float w0 = w01[2 * col], w1 = w01[2 * col + 1];
#pragma unroll
    for (int i = 0; i < 4; i++) {
#pragma unroll
      for (int r = 0; r < 4; r++) {
        int row = m0 + wr + i * 16 + quad * 4 + r;
        if (row < M) {
          float x = eluf(acca[i][j][r] + baj);
          float y = eluf(accb[i][j][r] + bbj);
          out[(size_t)row * N + col] = __float2bfloat16(x * w0 + y * w1);
        }
      }
    }
  }
}

// ---------------------------------------------------------------- layer-2 agg, XCD channel-sliced
__global__ __launch_bounds__(256) void agg2_kernel(
    const bf16* __restrict__ Ha, const bf16* __restrict__ Hb,  // ldH = 1024
    const int* __restrict__ off1, const int* __restrict__ cs1, const float* __restrict__ cw1,
    const int* __restrict__ off2, const int* __restrict__ cs2, const float* __restrict__ cw2,
    const float* __restrict__ dinv1, const float* __restrict__ dinv2,
    const float* __restrict__ ba, const float* __restrict__ bb,
    const float* __restrict__ w01, bf16* __restrict__ out, int n) {
  const int lin = blockIdx.x;
  const int slice = lin & 7;
  const int vg = lin >> 3;
  const int t = threadIdx.x;
  const int v = vg * 32 + t / 8;
  if (v >= n) return;
  const int c = slice * 64 + (t & 7) * 8;
  const bf16* __restrict__ baseA = Ha + c;
  const bf16* __restrict__ baseB = Hb + c;

  float a[8], b[8];
#pragma unroll
  for (int k = 0; k < 8; k++) { a[k] = 0.f; b[k] = 0.f; }

  gather_accum<1024>(baseA, cs1, cw1, off1[v], off1[v + 1], a);
  gather_accum<1024>(baseB, cs2, cw2, off2[v], off2[v + 1], b);

  short8 sa = *(const short8*)(baseA + (size_t)v * 1024);
  short8 sb = *(const short8*)(baseB + (size_t)v * 1024);
  const float dv1 = dinv1[v], dv2 = dinv2[v];

  short8 r;
#pragma unroll
  for (int k = 0; k < 8; k++) {
    float x = eluf(dv1 * a[k] + dv1 * dv1 * bf2f((unsigned short)sa[k]) + ba[c + k]);
    float y = eluf(dv2 * b[k] + dv2 * dv2 * bf2f((unsigned short)sb[k]) + bb[c + k]);
    r[k] = (short)__bfloat16_as_ushort(
        __float2bfloat16(x * w01[2 * (c + k)] + y * w01[2 * (c + k) + 1]));
  }
  *(short8*)(out + (size_t)v * 512 + c) = r;
}

// ---------------------------------------------------------------- layer-3 agg
template <int C, int LD, bool WU>
__global__ __launch_bounds__(256) void agg_out_kernel(
    const bf16* __restrict__ Ha, const bf16* __restrict__ Hb,
    const int* __restrict__ off1, const int* __restrict__ cs1, const float* __restrict__ cw1,
    const int* __restrict__ off2, const int* __restrict__ cs2, const float* __restrict__ cw2,
    const float* __restrict__ dinv1, const float* __restrict__ dinv2,
    const float* __restrict__ ba, const float* __restrict__ bb,
    const float* __restrict__ w01, void* __restrict__ out, int n,
    const int* __restrict__ outflag) {
  constexpr int TPV = C / 8;
  constexpr int G = 256 / TPV;
  const int t = threadIdx.x;
  int v = blockIdx.x * G + t / TPV;
  if (v >= n) return;
  if (WU) v = __builtin_amdgcn_readfirstlane(v);
  const int c = (t % TPV) * 8;
  const bf16* __restrict__ baseA = Ha + c;
  const bf16* __restrict__ baseB = Hb + c;

  float a[8], b[8];
#pragma unroll
  for (int k = 0; k < 8; k++) { a[k] = 0.f; b[k] = 0.f; }

  int s1 = off1[v], e1 = off1[v + 1];
  if (WU) { s1 = __builtin_amdgcn_readfirstlane(s1); e1 = __builtin_amdgcn_readfirstlane(e1); }
  gather_accum<LD>(baseA, cs1, cw1, s1, e1, a);
  int s2 = off2[v], e2 = off2[v + 1];
  if (WU) { s2 = __builtin_amdgcn_readfirstlane(s2); e2 = __builtin_amdgcn_readfirstlane(e2); }
  gather_accum<LD>(baseB, cs2, cw2, s2, e2, b);

  short8 sa = *(const short8*)(baseA + (size_t)v * LD);
  short8 sb = *(const short8*)(baseB + (size_t)v * LD);
  const float dv1 = dinv1[v], dv2 = dinv2[v];

  float r[8];
#pragma unroll
  for (int k = 0; k < 8; k++) {
    float x = eluf(dv1 * a[k] + dv1 * dv1 * bf2f((unsigned short)sa[k]) + ba[c + k]);
    float y = eluf(dv2 * b[k] + dv2 * dv2 * bf2f((unsigned short)sb[k]) + bb[c + k]);
    r[k] = x * w01[2 * (c + k)] + y * w01[2 * (c + k) + 1];
  }

  const bool out_f32 = (outflag != nullptr) && (*outflag != 0);
  size_t oi = (size_t)v * C + c;
  if (out_f32) {
    floatx4 lo = {r[0], r[1], r[2], r[3]};
    floatx4 hi = {r[4], r[5], r[6], r[7]};
    *(floatx4*)((float*)out + oi) = lo;
    *(floatx4*)((float*)out + oi + 4) = hi;
  } else {
    short8 rb;
#pragma unroll
    for (int k = 0; k < 8; k++)
      rb[k] = (short)__bfloat16_as_ushort(__float2bfloat16(r[k]));
    *(short8*)((bf16*)out + oi) = rb;
  }
}

// ---------------------------------------------------------------- host pipeline
extern "C" void kernel_launch(void* const* d_in, const int* in_sizes, int n_in,
                              void* d_out, int out_size, void* d_ws, size_t ws_size,
                              hipStream_t stream) {
  const void* X = d_in[0];
  const int* ei1 = (const int*)d_in[1];
  const int* ei2 = (const int*)d_in[2];
  const int n = in_sizes[0] / 512;
  const int E1 = in_sizes[1] / 2;
  const int E2 = in_sizes[2] / 2;
  const int* src1 = ei1;           const int* dst1 = ei1 + E1;
  const int* src2 = ei2;           const int* dst2 = ei2 + E2;

  auto rnd = [](size_t b) { return (b + 255) & ~(size_t)255; };
  char* p = (char*)d_ws;
  auto alloc = [&](size_t bytes) { char* r = p; p += rnd(bytes); return r; };

  int* flag = (int*)alloc(256);
  int* deg1 = (int*)alloc((size_t)n * 4);
  int* deg2 = (int*)alloc((size_t)n * 4);
  int* cur1 = (int*)alloc((size_t)n * 4);
  int* cur2 = (int*)alloc((size_t)n * 4);
  int* off1 = (int*)alloc((size_t)(n + 1) * 4);
  int* off2 = (int*)alloc((size_t)(n + 1) * 4);
  float* dinv1 = (float*)alloc((size_t)n * 4);
  float* dinv2 = (float*)alloc((size_t)n * 4);
  int* cs1 = (int*)alloc((size_t)E1 * 4);
  float* cw1 = (float*)alloc((size_t)E1 * 4);
  int* cs2 = (int*)alloc((size_t)E2 * 4);
  float* cw2 = (float*)alloc((size_t)E2 * 4);
  bf16* Wt11 = (bf16*)alloc((size_t)512 * 1024 * 2);
  bf16* Wt12 = (bf16*)alloc((size_t)512 * 1024 * 2);
  bf16* Wt2cat = (bf16*)alloc((size_t)1024 * 1024 * 2);
  bf16* Wt3cat = (bf16*)alloc((size_t)256 * 512 * 2);
  float* bf_[6]; int bsz[6] = {1024, 1024, 512, 512, 128, 128};
  for (int i = 0; i < 6; i++) bf_[i] = (float*)alloc((size_t)bsz[i] * 4);
  float* w01_[3]; int asz[3] = {2048, 1024, 256};
  for (int i = 0; i < 3; i++) w01_[i] = (float*)alloc((size_t)asz[i] * 4);
  bf16* Xb = (bf16*)alloc((size_t)n * 512 * 2);
  bf16* aggXa = (bf16*)alloc((size_t)n * 512 * 2);
  bf16* aggXb = (bf16*)alloc((size_t)n * 512 * 2);
  bf16* H1a = (bf16*)alloc((size_t)n * 1024 * 2);
  bf16* act1 = (bf16*)alloc((size_t)n * 1024 * 2);
  bf16* H2cat = H1a;
  bf16* act2 = aggXa;  // dead after gemm_l1f
  bf16* H3cat = aggXb; // dead after gemm_l1f

  // ---- prep: probe + zero counters
  int zwords = (int)(rnd((size_t)n * 4) * 4 / 4);
  probe_zero<<<1 + (zwords + 1023) / 1024, 256, 0, stream>>>(
      (const unsigned short*)X, flag, deg1, zwords);

  // ---- fused prep
  int xbBlocks = (n * 512) / 2048;
  int degBlocks = (E1 + E2 + 255) / 256;
  prep_all<<<2176 + xbBlocks + 20 + degBlocks, 256, 0, stream>>>(
      X, Xb, n * 512,
      d_in[3], d_in[5], d_in[7], d_in[9], d_in[11], d_in[13],
      Wt11, Wt12, Wt2cat, Wt3cat,
      d_in[4], d_in[6], d_in[8], d_in[10], d_in[12], d_in[14],
      d_in[15], d_in[16], d_in[17],
      bf_[0], bf_[1], bf_[2], bf_[3], bf_[4], bf_[5],
      w01_[0], w01_[1], w01_[2],
      dst1, E1, dst2, E2, deg1, deg2, flag);

  scan2_kernel<<<2, 1024, 0, stream>>>(deg1, off1, dinv1, deg2, off2, dinv2, n);
  csr_fused<<<(E1 + E2 + 255) / 256, 256, 0, stream>>>(src1, dst1, E1, src2, dst2, E2,
                                                       off1, cur1, dinv1, cs1, cw1,
                                                       off2, cur2, dinv2, cs2, cw2);

  const int mtiles = (n + 127) / 128;
  auto swgrid = [](int mtTotal, int ntiles) {
    return 8 * ntiles * ((mtTotal + 7) / 8);
  };
  const int vg32 = 8 * ((n + 31) / 32);
  // ---- layer 1
  aggx_kernel<<<vg32, 256, 0, stream>>>(Xb, off1, cs1, cw1, off2, cs2, cw2,
                                        dinv1, dinv2, aggXa, aggXb, n);
  gemm_l1f<<<swgrid(mtiles, 8), 512, 0, stream>>>(
      aggXa, Wt11, aggXb, Wt12, bf_[0], bf_[1], w01_[0], act1, n, 512, 1024, mtiles);
  // ---- layer 2 (BK=64 GEMM)
  gemm128_sw<<<swgrid(mtiles, 8), 256, 0, stream>>>(
      act1, Wt2cat, H2cat, act1, Wt2cat, H2cat, n, 1024, 1024, mtiles, mtiles, 3);
  agg2_kernel<<<vg32, 256, 0, stream>>>(H2cat, H2cat + 512,
                                        off1, cs1, cw1, off2, cs2, cw2,
                                        dinv1, dinv2, bf_[2], bf_[3], w01_[1], act2, n);
  // ---- layer 3 (BK=64 GEMM)
  gemm128_sw<<<swgrid(mtiles, 2), 256, 0, stream>>>(
      act2, Wt3cat, H3cat, act2, Wt3cat, H3cat, n, 512, 256, mtiles, mtiles, 1);
  agg_out_kernel<128, 256, false><<<(n + 15) / 16, 256, 0, stream>>>(
      H3cat, H3cat + 128, off1, cs1, cw1, off2, cs2, cw2,
      dinv1, dinv2, bf_[4], bf_[5], w01_[2], d_out, n, flag);
}